// Round 5
// baseline (1115.743 us; speedup 1.0000x reference)
//
#include <hip/hip_runtime.h>
#include <hip/hip_bf16.h>
#include <stdint.h>

#define CDIM 192
#define KDIM 960
#define HW   65536
#define WI   256

// workspace: Wb bf16 (368640 B) + bias f32 (768 B) + flag
#define OFF_BIAS 368640u
#define OFF_FLAG 369408u
#define NEED_WS  369472u

// fused-kernel LDS: x slices stored TRANSPOSED [px_local:132][c:32] bf16,
// row stride 80 B (64 B data + 16 B pad). No W in LDS (W goes global->reg).
#define ROW_B    80
#define SLICE_B  10560   // 132 * 80
#define LDS_TOT  31680   // 3 * SLICE_B  -> up to 5 blocks/CU

typedef __attribute__((ext_vector_type(8))) short short8;
typedef __attribute__((ext_vector_type(4))) float floatx4;

__device__ __forceinline__ uint16_t f2b(float v) {
    __hip_bfloat16 h = __float2bfloat16(v);
    return *reinterpret_cast<uint16_t*>(&h);
}

// ---------------- dtype detector: bf16-packed vs fp32, via low-halfword exponent stats ----------
__global__ __launch_bounds__(256) void detect_kernel(const uint32_t* __restrict__ xw,
                                                     int* __restrict__ flag) {
    __shared__ int cnt;
    if (threadIdx.x == 0) cnt = 0;
    __syncthreads();
    int local = 0;
    #pragma unroll
    for (int i = 0; i < 4; ++i) {
        int s = threadIdx.x * 4 + i;                   // 0..1023
        uint32_t d = xw[(size_t)s * 24571];            // max dword 25,136,133 < 25,165,824
        uint32_t e = (d >> 7) & 0xFF;                  // bf16 exponent field of LOW halfword
        if (e >= 110 && e <= 130) ++local;             // plausible for N(0,1) bf16
    }
    atomicAdd(&cnt, local);
    __syncthreads();
    if (threadIdx.x == 0) *flag = (cnt >= 512) ? 1 : 0;   // 1 = bf16 buffers, 0 = fp32 buffers
}

// ---------------- prep: canonicalize W -> bf16, bias -> f32 (so GEMM is dtype-free) ------------
__global__ __launch_bounds__(256) void prep_kernel(const void* __restrict__ Wsrc,
                                                   const void* __restrict__ bsrc,
                                                   __hip_bfloat16* __restrict__ Wb,
                                                   float* __restrict__ bfp,
                                                   const int* __restrict__ flag) {
    const int f = *flag;
    if (blockIdx.x < 720) {
        int i = blockIdx.x * 256 + threadIdx.x;        // < 184320
        float v = f ? __bfloat162float(((const __hip_bfloat16*)Wsrc)[i])
                    : ((const float*)Wsrc)[i];
        Wb[i] = __float2bfloat16(v);
    } else if (threadIdx.x < CDIM) {
        int j = threadIdx.x;
        bfp[j] = f ? __bfloat162float(((const __hip_bfloat16*)bsrc)[j])
                   : ((const float*)bsrc)[j];
    }
}

// ---------------- fused transpose+GEMM, W in registers, barrier-free inner loop ----------------
// Out[o][p] = sum_s sum_c W[o][s*192+c] * x[c][p + dp(s)], x staged per 32-c block in LDS.
// W fragment per lane: Wm[o][(s*6+j)*32 + quad*8 .. +8] -- 16 B contiguous, 64 B per 16-lane
// group, L2-resident (368 KB shared by all blocks). No LDS staging for W -> no per-step
// barriers; only 2 __syncthreads per j-boundary for the x-slice LDS refill.
__global__ __launch_bounds__(256, 4) void fused_kernel(const void* __restrict__ xsrc,
                                                       const __hip_bfloat16* __restrict__ Wm,
                                                       const float* __restrict__ biasf,
                                                       void* __restrict__ outv,
                                                       const int* __restrict__ flag) {
    __shared__ char xsl[LDS_TOT];   // 31680 B
    const int f = *flag;
    const int tid  = threadIdx.x;
    const int lane = tid & 63, wave = tid >> 6;
    const int quad = lane >> 4, l15 = lane & 15;

    // XCD-aware bijective swizzle: consecutive wg -> h-adjacent, L2-local halo reuse
    const int nwg  = (int)gridDim.x;                 // 2048, % 8 == 0
    const int bid0 = (int)blockIdx.x;
    const int wg   = (bid0 & 7) * (nwg >> 3) + (bid0 >> 3);

    const int bb = wg >> 9;                          // plane 0..3
    const int r  = wg & 511;
    const int h  = r >> 1;
    const int w0 = (r & 1) << 7;
    const int p0 = h * WI + w0;
    const int obase = (wave >> 1) * 96;
    const int nbase = (wave & 1) * 64;

    // per-lane W fragment base: af[mt](j,s) = *(short8*)(wbase[mt] + (s*6+j)*64)
    const char* wbase[6];
    #pragma unroll
    for (int mt = 0; mt < 6; ++mt) {
        int o = obase + mt * 16 + l15;
        wbase[mt] = (const char*)Wm + (size_t)o * (KDIM * 2) + quad * 16;
    }

    // B-fragment geometry: pl = local out-col 0..127
    int pxa[4]; bool w255[4], wzero[4];
    #pragma unroll
    for (int nt = 0; nt < 4; ++nt) {
        int pl = nbase + nt * 16 + l15;
        pxa[nt]   = (pl + 1) * ROW_B;                // px_local = pl+1 (center)
        w255[nt]  = ((w0 + pl) == 255);
        wzero[nt] = ((w0 + pl) == 0);
    }

    // staging geometry: main threads cover px_local 1..128 x 16 c each
    const int scc  = tid >> 7;                       // c-half 0/1
    const int spx  = (tid & 127) + 1;                // px_local 1..128
    const int scol = w0 + (tid & 127);               // global col, always 0..255
    // edge threads (tid<64) cover px_local 0 (col w0-1) and 129 (col w0+128)
    const int ec = tid >> 1, ee = tid & 1;
    int ecol = ee ? (w0 + 128) : (w0 - 1);
    if (ecol < 0) ecol = 0;
    if (ecol > 255) ecol = 255;                      // clamped cols are killed at consume
    const int epx = ee ? 129 : 0;

    const size_t esz = f ? 2u : 4u;
    const char* xp = (const char*)xsrc + (size_t)bb * CDIM * HW * esz;

    int hr[3];
    #pragma unroll
    for (int rr = 0; rr < 3; ++rr) {
        int v = h - 1 + rr;
        hr[rr] = v < 0 ? 0 : (v > 255 ? 255 : v);    // clamped rows are killed at consume
    }

    floatx4 acc[6][4];
    #pragma unroll
    for (int mt = 0; mt < 6; ++mt)
        #pragma unroll
        for (int nt = 0; nt < 4; ++nt)
            acc[mt][nt] = (floatx4){0.f, 0.f, 0.f, 0.f};

#define STAGE(JJ)                                                                          \
    {                                                                                      \
        const int c0 = (JJ) * 32;                                                          \
        _Pragma("unroll")                                                                  \
        for (int rr = 0; rr < 3; ++rr) {                                                   \
            uint32_t tmp[16];                                                              \
            const size_t rowoff = (size_t)hr[rr] * WI;                                     \
            if (f) {                                                                       \
                const uint16_t* xg = (const uint16_t*)xp;                                  \
                _Pragma("unroll")                                                          \
                for (int cc = 0; cc < 16; ++cc)                                            \
                    tmp[cc] = xg[(size_t)(c0 + scc * 16 + cc) * HW + rowoff + scol];       \
            } else {                                                                       \
                const float* xg = (const float*)xp;                                        \
                _Pragma("unroll")                                                          \
                for (int cc = 0; cc < 16; ++cc)                                            \
                    tmp[cc] = f2b(xg[(size_t)(c0 + scc * 16 + cc) * HW + rowoff + scol]);  \
            }                                                                              \
            uint4 q0, q1;                                                                  \
            q0.x = tmp[0] | (tmp[1] << 16);  q0.y = tmp[2] | (tmp[3] << 16);               \
            q0.z = tmp[4] | (tmp[5] << 16);  q0.w = tmp[6] | (tmp[7] << 16);               \
            q1.x = tmp[8] | (tmp[9] << 16);  q1.y = tmp[10] | (tmp[11] << 16);             \
            q1.z = tmp[12] | (tmp[13] << 16); q1.w = tmp[14] | (tmp[15] << 16);            \
            char* base = xsl + rr * SLICE_B + spx * ROW_B + scc * 32;                      \
            *(uint4*)(base)      = q0;                                                     \
            *(uint4*)(base + 16) = q1;                                                     \
        }                                                                                  \
        if (tid < 64) {                                                                    \
            _Pragma("unroll")                                                              \
            for (int rr = 0; rr < 3; ++rr) {                                               \
                const size_t gi = (size_t)(c0 + ec) * HW + (size_t)hr[rr] * WI + ecol;     \
                uint16_t v = f ? ((const uint16_t*)xp)[gi]                                 \
                               : f2b(((const float*)xp)[gi]);                              \
                *(uint16_t*)(xsl + rr * SLICE_B + epx * ROW_B + ec * 2) = v;               \
            }                                                                              \
        }                                                                                  \
    }

    STAGE(0)
    __syncthreads();

    for (int j = 0; j < 6; ++j) {
        #pragma unroll
        for (int s = 0; s < 5; ++s) {
            // W fragments straight from global (L2-resident); no barriers needed
            short8 af[6];
            #pragma unroll
            for (int mt = 0; mt < 6; ++mt)
                af[mt] = *(const short8*)(wbase[mt] + (size_t)(s * 6 + j) * 64);

            // B-fragments from LDS x-slices: slice/col-shift per s
            const int so   = (s == 3) ? 2 * SLICE_B : (s == 4) ? 0 : SLICE_B;
            const int dw80 = (s == 1) ? ROW_B : (s == 2) ? -ROW_B : 0;
            const bool skip = (s == 3 && h == 255) || (s == 4 && h == 0);
            short8 bf[4];
            #pragma unroll
            for (int nt = 0; nt < 4; ++nt) {
                short8 v = *(const short8*)(xsl + so + pxa[nt] + dw80 + quad * 16);
                const bool kill = skip || (s == 1 && w255[nt]) || (s == 2 && wzero[nt]);
                bf[nt] = kill ? (short8){0, 0, 0, 0, 0, 0, 0, 0} : v;
            }

            __builtin_amdgcn_s_setprio(1);
            #pragma unroll
            for (int mt = 0; mt < 6; ++mt)
                #pragma unroll
                for (int nt = 0; nt < 4; ++nt)
                    acc[mt][nt] = __builtin_amdgcn_mfma_f32_16x16x32_bf16(
                        af[mt], bf[nt], acc[mt][nt], 0, 0, 0);
            __builtin_amdgcn_s_setprio(0);
        }
        if (j < 5) {
            __syncthreads();                        // all reads of xs[j] done
            STAGE(j + 1)
            __syncthreads();                        // xs[j+1] visible
        }
    }

    // epilogue: + bias; D layout: row(o) = quad*4+reg, col(px) = lane&15
    #pragma unroll
    for (int mt = 0; mt < 6; ++mt) {
        int o0 = obase + mt * 16 + quad * 4;
        float bv[4];
        #pragma unroll
        for (int rr = 0; rr < 4; ++rr) bv[rr] = biasf[o0 + rr];
        #pragma unroll
        for (int nt = 0; nt < 4; ++nt) {
            int px = nbase + nt * 16 + l15;
            size_t base = ((size_t)(bb * CDIM + o0) * HW) + p0 + px;
            if (f) {
                __hip_bfloat16* out = (__hip_bfloat16*)outv;
                #pragma unroll
                for (int rr = 0; rr < 4; ++rr)
                    out[base + (size_t)rr * HW] = __float2bfloat16(acc[mt][nt][rr] + bv[rr]);
            } else {
                float* out = (float*)outv;
                #pragma unroll
                for (int rr = 0; rr < 4; ++rr)
                    out[base + (size_t)rr * HW] = acc[mt][nt][rr] + bv[rr];
            }
        }
    }
#undef STAGE
}

// ---------------- fallback: naive direct conv, dtype-aware, no big workspace -------------------
__global__ __launch_bounds__(256) void fallback_kernel(const void* __restrict__ xv,
                                                       const void* __restrict__ Wv,
                                                       const void* __restrict__ bv,
                                                       void* __restrict__ outv,
                                                       const int* __restrict__ flag) {
    __shared__ float Wl[KDIM];
    const int f = *flag;
    const int tid = threadIdx.x;
    const int bid = blockIdx.x;
    const int h = bid & 255;
    const int bo = bid >> 8;
    const int o = bo % CDIM;
    const int b = bo / CDIM;
    if (f) {
        const __hip_bfloat16* W16 = (const __hip_bfloat16*)Wv;
        for (int i = tid; i < KDIM; i += 256) Wl[i] = __bfloat162float(W16[(size_t)o * KDIM + i]);
    } else {
        const float* W32 = (const float*)Wv;
        for (int i = tid; i < KDIM; i += 256) Wl[i] = W32[(size_t)o * KDIM + i];
    }
    __syncthreads();
    const size_t pb = (size_t)b * CDIM * HW + (size_t)h * WI + tid;
    float acc = f ? __bfloat162float(((const __hip_bfloat16*)bv)[o]) : ((const float*)bv)[o];
    if (f) {
        const __hip_bfloat16* x = (const __hip_bfloat16*)xv;
        for (int c = 0; c < CDIM; ++c) {
            const __hip_bfloat16* xp = x + pb + (size_t)c * HW;
            float ctr = __bfloat162float(xp[0]);
            float rgt = (tid < 255) ? __bfloat162float(xp[1])   : 0.f;
            float lft = (tid > 0)   ? __bfloat162float(xp[-1])  : 0.f;
            float dwn = (h < 255)   ? __bfloat162float(xp[WI])  : 0.f;
            float up  = (h > 0)     ? __bfloat162float(xp[-WI]) : 0.f;
            acc += ctr * Wl[c] + rgt * Wl[192 + c] + lft * Wl[384 + c]
                 + dwn * Wl[576 + c] + up * Wl[768 + c];
        }
    } else {
        const float* x = (const float*)xv;
        for (int c = 0; c < CDIM; ++c) {
            const float* xp = x + pb + (size_t)c * HW;
            float ctr = xp[0];
            float rgt = (tid < 255) ? xp[1]   : 0.f;
            float lft = (tid > 0)   ? xp[-1]  : 0.f;
            float dwn = (h < 255)   ? xp[WI]  : 0.f;
            float up  = (h > 0)     ? xp[-WI] : 0.f;
            acc += ctr * Wl[c] + rgt * Wl[192 + c] + lft * Wl[384 + c]
                 + dwn * Wl[576 + c] + up * Wl[768 + c];
        }
    }
    size_t oidx = (size_t)bo * HW + (size_t)h * WI + tid;
    if (f) ((__hip_bfloat16*)outv)[oidx] = __float2bfloat16(acc);
    else   ((float*)outv)[oidx] = acc;
}

extern "C" void kernel_launch(void* const* d_in, const int* in_sizes, int n_in,
                              void* d_out, int out_size, void* d_ws, size_t ws_size,
                              hipStream_t stream) {
    const uint32_t* xw = (const uint32_t*)d_in[0];
    char* ws = (char*)d_ws;

    if (ws_size >= NEED_WS) {
        __hip_bfloat16* Wb = (__hip_bfloat16*)ws;
        float* bfp = (float*)(ws + OFF_BIAS);
        int* flag  = (int*)(ws + OFF_FLAG);
        detect_kernel<<<1, 256, 0, stream>>>(xw, flag);
        prep_kernel<<<721, 256, 0, stream>>>(d_in[1], d_in[2], Wb, bfp, flag);
        fused_kernel<<<2048, 256, 0, stream>>>(d_in[0], Wb, bfp, d_out, flag);
    } else {
        int* flag = (int*)ws;
        detect_kernel<<<1, 256, 0, stream>>>(xw, flag);
        fallback_kernel<<<4 * CDIM * 256, 256, 0, stream>>>(d_in[0], d_in[1], d_in[2],
                                                            d_out, flag);
    }
}

// Round 6
// 525.680 us; speedup vs baseline: 2.1225x; 2.1225x over previous
//
#include <hip/hip_runtime.h>
#include <hip/hip_bf16.h>
#include <stdint.h>

#define CDIM 192
#define KDIM 960
#define HW   65536
#define WI   256

// workspace: Wb bf16 (368640 B) + bias f32 (768 B) + flag
#define OFF_BIAS 368640u
#define OFF_FLAG 369408u
#define NEED_WS  369472u

// fused-kernel LDS: x slices TRANSPOSED [px_local:66][c:32] bf16, row stride 80 B
// (64 B data + 16 B pad -> 8-bank spread). 3 slices (h-1,h,h+1). 15840 B total.
#define ROW_B    80
#define SLICE_B  5280    // 66 * 80
#define LDS_TOT  15840   // 3 * SLICE_B

typedef __attribute__((ext_vector_type(8))) short short8;
typedef __attribute__((ext_vector_type(4))) float floatx4;

__device__ __forceinline__ uint16_t f2b(float v) {
    __hip_bfloat16 h = __float2bfloat16(v);
    return *reinterpret_cast<uint16_t*>(&h);
}

// ---------------- dtype detector: bf16-packed vs fp32, via low-halfword exponent stats ----------
__global__ __launch_bounds__(256) void detect_kernel(const uint32_t* __restrict__ xw,
                                                     int* __restrict__ flag) {
    __shared__ int cnt;
    if (threadIdx.x == 0) cnt = 0;
    __syncthreads();
    int local = 0;
    #pragma unroll
    for (int i = 0; i < 4; ++i) {
        int s = threadIdx.x * 4 + i;                   // 0..1023
        uint32_t d = xw[(size_t)s * 24571];            // max dword 25,136,133 < 25,165,824
        uint32_t e = (d >> 7) & 0xFF;                  // bf16 exponent field of LOW halfword
        if (e >= 110 && e <= 130) ++local;             // plausible for N(0,1) bf16
    }
    atomicAdd(&cnt, local);
    __syncthreads();
    if (threadIdx.x == 0) *flag = (cnt >= 512) ? 1 : 0;   // 1 = bf16 buffers, 0 = fp32 buffers
}

// ---------------- prep: canonicalize W -> bf16, bias -> f32 (so GEMM is dtype-free) ------------
__global__ __launch_bounds__(256) void prep_kernel(const void* __restrict__ Wsrc,
                                                   const void* __restrict__ bsrc,
                                                   __hip_bfloat16* __restrict__ Wb,
                                                   float* __restrict__ bfp,
                                                   const int* __restrict__ flag) {
    const int f = *flag;
    if (blockIdx.x < 720) {
        int i = blockIdx.x * 256 + threadIdx.x;        // < 184320
        float v = f ? __bfloat162float(((const __hip_bfloat16*)Wsrc)[i])
                    : ((const float*)Wsrc)[i];
        Wb[i] = __float2bfloat16(v);
    } else if (threadIdx.x < CDIM) {
        int j = threadIdx.x;
        bfp[j] = f ? __bfloat162float(((const __hip_bfloat16*)bsrc)[j])
                   : ((const float*)bsrc)[j];
    }
}

// ---------------- fused transpose+GEMM, W in registers, barrier-free inner loop ----------------
// Block tile: 192 o x 64 px (grid 4096).  Wave tile: 48 o x 64 px -> acc[3][4] = 48 regs
// (R5 lesson: 96-reg acc + forced occupancy = spill; this halves the footprint instead).
// W fragment per lane straight from global (L2-resident, 368 KB): no W-LDS, no per-step
// barriers; only 2 __syncthreads per j-boundary for the x-slice refill.
__global__ __launch_bounds__(256, 3) void fused_kernel(const void* __restrict__ xsrc,
                                                       const __hip_bfloat16* __restrict__ Wm,
                                                       const float* __restrict__ biasf,
                                                       void* __restrict__ outv,
                                                       const int* __restrict__ flag) {
    __shared__ char xsl[LDS_TOT];   // 15840 B
    const int f = *flag;
    const int tid  = threadIdx.x;
    const int lane = tid & 63, wave = tid >> 6;       // wave 0..3 = o-tile
    const int quad = lane >> 4, l15 = lane & 15;

    // XCD-aware bijective swizzle: consecutive wg -> w/h-adjacent, L2-local halo reuse
    const int nwg  = (int)gridDim.x;                  // 4096, % 8 == 0
    const int bid0 = (int)blockIdx.x;
    const int wg   = (bid0 & 7) * (nwg >> 3) + (bid0 >> 3);

    const int bb = wg >> 10;                          // plane 0..3
    const int r  = wg & 1023;
    const int h  = r >> 2;
    const int w0 = (r & 3) << 6;                      // px-quarter 0/64/128/192
    const int p0 = h * WI + w0;
    const int obase = wave * 48;

    // per-lane W fragment bases: af[mt](step) = *(short8*)(wbase[mt] + step*64)
    const char* wbase[3];
    #pragma unroll
    for (int mt = 0; mt < 3; ++mt) {
        int o = obase + mt * 16 + l15;
        wbase[mt] = (const char*)Wm + (size_t)o * (KDIM * 2) + quad * 16;
    }

    // B-fragment geometry: pl = local out-col 0..63 (whole wave spans the px tile)
    int pxa[4]; bool w255[4], wzero[4];
    #pragma unroll
    for (int nt = 0; nt < 4; ++nt) {
        int pl = nt * 16 + l15;
        pxa[nt]   = (pl + 1) * ROW_B;                 // px_local = pl+1 (center)
        w255[nt]  = ((w0 + pl) == 255);
        wzero[nt] = ((w0 + pl) == 0);
    }

    // staging geometry: main threads cover px_local 1..64 x 8 c each per row
    const int scc  = tid >> 6;                        // c-octet 0..3
    const int spx  = (tid & 63) + 1;                  // px_local 1..64
    const int scol = w0 + (tid & 63);                 // global col 0..255
    // edge threads (tid<64) cover px_local 0 (col w0-1) and 65 (col w0+64)
    const int ec = tid >> 1, ee = tid & 1;            // ec = c 0..31
    int ecol = ee ? (w0 + 64) : (w0 - 1);
    if (ecol < 0) ecol = 0;
    if (ecol > 255) ecol = 255;                       // clamped cols are killed at consume
    const int epx = ee ? 65 : 0;

    const size_t esz = f ? 2u : 4u;
    const char* xp = (const char*)xsrc + (size_t)bb * CDIM * HW * esz;

    int hr[3];
    #pragma unroll
    for (int rr = 0; rr < 3; ++rr) {
        int v = h - 1 + rr;
        hr[rr] = v < 0 ? 0 : (v > 255 ? 255 : v);     // clamped rows are killed at consume
    }

    floatx4 acc[3][4];
    #pragma unroll
    for (int mt = 0; mt < 3; ++mt)
        #pragma unroll
        for (int nt = 0; nt < 4; ++nt)
            acc[mt][nt] = (floatx4){0.f, 0.f, 0.f, 0.f};

#define STAGE(JJ)                                                                          \
    {                                                                                      \
        const int c0 = (JJ) * 32;                                                          \
        _Pragma("unroll")                                                                  \
        for (int rr = 0; rr < 3; ++rr) {                                                   \
            uint32_t tmp[8];                                                               \
            const size_t rowoff = (size_t)hr[rr] * WI;                                     \
            if (f) {                                                                       \
                const uint16_t* xg = (const uint16_t*)xp;                                  \
                _Pragma("unroll")                                                          \
                for (int cc = 0; cc < 8; ++cc)                                             \
                    tmp[cc] = xg[(size_t)(c0 + scc * 8 + cc) * HW + rowoff + scol];        \
            } else {                                                                       \
                const float* xg = (const float*)xp;                                        \
                _Pragma("unroll")                                                          \
                for (int cc = 0; cc < 8; ++cc)                                             \
                    tmp[cc] = f2b(xg[(size_t)(c0 + scc * 8 + cc) * HW + rowoff + scol]);   \
            }                                                                              \
            uint4 q;                                                                       \
            q.x = tmp[0] | (tmp[1] << 16);  q.y = tmp[2] | (tmp[3] << 16);                 \
            q.z = tmp[4] | (tmp[5] << 16);  q.w = tmp[6] | (tmp[7] << 16);                 \
            *(uint4*)(xsl + rr * SLICE_B + spx * ROW_B + scc * 16) = q;                    \
        }                                                                                  \
        if (tid < 64) {                                                                    \
            _Pragma("unroll")                                                              \
            for (int rr = 0; rr < 3; ++rr) {                                               \
                const size_t gi = (size_t)(c0 + ec) * HW + (size_t)hr[rr] * WI + ecol;     \
                uint16_t v = f ? ((const uint16_t*)xp)[gi]                                 \
                               : f2b(((const float*)xp)[gi]);                              \
                *(uint16_t*)(xsl + rr * SLICE_B + epx * ROW_B + ec * 2) = v;               \
            }                                                                              \
        }                                                                                  \
    }

    STAGE(0)
    __syncthreads();

    for (int j = 0; j < 6; ++j) {
        #pragma unroll
        for (int s = 0; s < 5; ++s) {
            // W fragments straight from global (L2-resident); no barriers needed
            short8 af[3];
            #pragma unroll
            for (int mt = 0; mt < 3; ++mt)
                af[mt] = *(const short8*)(wbase[mt] + (size_t)(s * 6 + j) * 64);

            // B-fragments from LDS x-slices: slice/col-shift per s
            const int so   = (s == 3) ? 2 * SLICE_B : (s == 4) ? 0 : SLICE_B;
            const int dw80 = (s == 1) ? ROW_B : (s == 2) ? -ROW_B : 0;
            const bool skip = (s == 3 && h == 255) || (s == 4 && h == 0);
            short8 bf[4];
            #pragma unroll
            for (int nt = 0; nt < 4; ++nt) {
                short8 v = *(const short8*)(xsl + so + pxa[nt] + dw80 + quad * 16);
                const bool kill = skip || (s == 1 && w255[nt]) || (s == 2 && wzero[nt]);
                bf[nt] = kill ? (short8){0, 0, 0, 0, 0, 0, 0, 0} : v;
            }

            __builtin_amdgcn_s_setprio(1);
            #pragma unroll
            for (int mt = 0; mt < 3; ++mt)
                #pragma unroll
                for (int nt = 0; nt < 4; ++nt)
                    acc[mt][nt] = __builtin_amdgcn_mfma_f32_16x16x32_bf16(
                        af[mt], bf[nt], acc[mt][nt], 0, 0, 0);
            __builtin_amdgcn_s_setprio(0);
        }
        if (j < 5) {
            __syncthreads();                        // all reads of xs[j] done
            STAGE(j + 1)
            __syncthreads();                        // xs[j+1] visible
        }
    }

    // epilogue: + bias; D layout: row(o) = quad*4+reg, col(px) = lane&15
    #pragma unroll
    for (int mt = 0; mt < 3; ++mt) {
        int o0 = obase + mt * 16 + quad * 4;
        float bv[4];
        #pragma unroll
        for (int rr = 0; rr < 4; ++rr) bv[rr] = biasf[o0 + rr];
        #pragma unroll
        for (int nt = 0; nt < 4; ++nt) {
            int px = nt * 16 + l15;
            size_t base = ((size_t)(bb * CDIM + o0) * HW) + p0 + px;
            if (f) {
                __hip_bfloat16* out = (__hip_bfloat16*)outv;
                #pragma unroll
                for (int rr = 0; rr < 4; ++rr)
                    out[base + (size_t)rr * HW] = __float2bfloat16(acc[mt][nt][rr] + bv[rr]);
            } else {
                float* out = (float*)outv;
                #pragma unroll
                for (int rr = 0; rr < 4; ++rr)
                    out[base + (size_t)rr * HW] = acc[mt][nt][rr] + bv[rr];
            }
        }
    }
#undef STAGE
}

// ---------------- fallback: naive direct conv, dtype-aware, no big workspace -------------------
__global__ __launch_bounds__(256) void fallback_kernel(const void* __restrict__ xv,
                                                       const void* __restrict__ Wv,
                                                       const void* __restrict__ bv,
                                                       void* __restrict__ outv,
                                                       const int* __restrict__ flag) {
    __shared__ float Wl[KDIM];
    const int f = *flag;
    const int tid = threadIdx.x;
    const int bid = blockIdx.x;
    const int h = bid & 255;
    const int bo = bid >> 8;
    const int o = bo % CDIM;
    const int b = bo / CDIM;
    if (f) {
        const __hip_bfloat16* W16 = (const __hip_bfloat16*)Wv;
        for (int i = tid; i < KDIM; i += 256) Wl[i] = __bfloat162float(W16[(size_t)o * KDIM + i]);
    } else {
        const float* W32 = (const float*)Wv;
        for (int i = tid; i < KDIM; i += 256) Wl[i] = W32[(size_t)o * KDIM + i];
    }
    __syncthreads();
    const size_t pb = (size_t)b * CDIM * HW + (size_t)h * WI + tid;
    float acc = f ? __bfloat162float(((const __hip_bfloat16*)bv)[o]) : ((const float*)bv)[o];
    if (f) {
        const __hip_bfloat16* x = (const __hip_bfloat16*)xv;
        for (int c = 0; c < CDIM; ++c) {
            const __hip_bfloat16* xp = x + pb + (size_t)c * HW;
            float ctr = __bfloat162float(xp[0]);
            float rgt = (tid < 255) ? __bfloat162float(xp[1])   : 0.f;
            float lft = (tid > 0)   ? __bfloat162float(xp[-1])  : 0.f;
            float dwn = (h < 255)   ? __bfloat162float(xp[WI])  : 0.f;
            float up  = (h > 0)     ? __bfloat162float(xp[-WI]) : 0.f;
            acc += ctr * Wl[c] + rgt * Wl[192 + c] + lft * Wl[384 + c]
                 + dwn * Wl[576 + c] + up * Wl[768 + c];
        }
    } else {
        const float* x = (const float*)xv;
        for (int c = 0; c < CDIM; ++c) {
            const float* xp = x + pb + (size_t)c * HW;
            float ctr = xp[0];
            float rgt = (tid < 255) ? xp[1]   : 0.f;
            float lft = (tid > 0)   ? xp[-1]  : 0.f;
            float dwn = (h < 255)   ? xp[WI]  : 0.f;
            float up  = (h > 0)     ? xp[-WI] : 0.f;
            acc += ctr * Wl[c] + rgt * Wl[192 + c] + lft * Wl[384 + c]
                 + dwn * Wl[576 + c] + up * Wl[768 + c];
        }
    }
    size_t oidx = (size_t)bo * HW + (size_t)h * WI + tid;
    if (f) ((__hip_bfloat16*)outv)[oidx] = __float2bfloat16(acc);
    else   ((float*)outv)[oidx] = acc;
}

extern "C" void kernel_launch(void* const* d_in, const int* in_sizes, int n_in,
                              void* d_out, int out_size, void* d_ws, size_t ws_size,
                              hipStream_t stream) {
    const uint32_t* xw = (const uint32_t*)d_in[0];
    char* ws = (char*)d_ws;

    if (ws_size >= NEED_WS) {
        __hip_bfloat16* Wb = (__hip_bfloat16*)ws;
        float* bfp = (float*)(ws + OFF_BIAS);
        int* flag  = (int*)(ws + OFF_FLAG);
        detect_kernel<<<1, 256, 0, stream>>>(xw, flag);
        prep_kernel<<<721, 256, 0, stream>>>(d_in[1], d_in[2], Wb, bfp, flag);
        fused_kernel<<<4096, 256, 0, stream>>>(d_in[0], Wb, bfp, d_out, flag);
    } else {
        int* flag = (int*)ws;
        detect_kernel<<<1, 256, 0, stream>>>(xw, flag);
        fallback_kernel<<<4 * CDIM * 256, 256, 0, stream>>>(d_in[0], d_in[1], d_in[2],
                                                            d_out, flag);
    }
}